// Round 1
// baseline (869.015 us; speedup 1.0000x reference)
//
#include <hip/hip_runtime.h>

#define NN 50000
#define NE 600000
#define F_IN 57
#define HID 128
#define NEG 0.2f

// ---- ordered-uint encoding for float atomicMax ----
__device__ __forceinline__ unsigned fenc(float f) {
    unsigned b = __float_as_uint(f);
    return (b & 0x80000000u) ? ~b : (b | 0x80000000u);
}
__device__ __forceinline__ float fdec(unsigned k) {
    unsigned b = (k & 0x80000000u) ? (k & 0x7FFFFFFFu) : ~k;
    return __uint_as_float(b);
}

// K1: h = x @ W_gat ; hs = h . a_src ; hd = h . a_dst   (one block / node, 128 thr)
__global__ void k_gat_in(const float* __restrict__ x, const float* __restrict__ Wg,
                         const float* __restrict__ a_s, const float* __restrict__ a_d,
                         float* __restrict__ h, float* __restrict__ hs, float* __restrict__ hd) {
    int row = blockIdx.x;
    int t = threadIdx.x;
    __shared__ float xs[F_IN];
    if (t < F_IN) xs[t] = x[row * F_IN + t];
    __syncthreads();
    float acc = 0.f;
#pragma unroll
    for (int k = 0; k < F_IN; ++k) acc = fmaf(xs[k], Wg[k * HID + t], acc);
    h[(size_t)row * HID + t] = acc;
    float ps = acc * a_s[t];
    float pd = acc * a_d[t];
    for (int o = 32; o > 0; o >>= 1) { ps += __shfl_down(ps, o); pd += __shfl_down(pd, o); }
    __shared__ float r[4];
    int w = t >> 6;
    if ((t & 63) == 0) { r[w] = ps; r[2 + w] = pd; }
    __syncthreads();
    if (t == 0) { hs[row] = r[0] + r[1]; hd[row] = r[2] + r[3]; }
}

// K2: per-edge logit (leaky relu) + segment max via atomicMax on encoded uint
__global__ void k_logit_max(const int* __restrict__ src, const int* __restrict__ dst,
                            const float* __restrict__ hs, const float* __restrict__ hd,
                            float* __restrict__ logitbuf, unsigned* __restrict__ lmaxk, int nE) {
    int e = blockIdx.x * blockDim.x + threadIdx.x;
    if (e >= nE) return;
    int s, d;
    if (e < NE) { s = src[e]; d = dst[e]; } else { s = d = e - NE; }
    float v = hs[s] + hd[d];
    v = v >= 0.f ? v : NEG * v;
    logitbuf[e] = v;
    atomicMax(&lmaxk[d], fenc(v));
}

// K3: ex = exp(logit - lmax[dst]); denom[dst] += ex  (logitbuf overwritten with ex)
__global__ void k_exp_sum(const int* __restrict__ dst, const unsigned* __restrict__ lmaxk,
                          float* __restrict__ exbuf, float* __restrict__ denom, int nE) {
    int e = blockIdx.x * blockDim.x + threadIdx.x;
    if (e >= nE) return;
    int d = (e < NE) ? dst[e] : e - NE;
    float m = fdec(lmaxk[d]);
    float ex = __expf(exbuf[e] - m);
    exbuf[e] = ex;
    atomicAdd(&denom[d], ex);
}

// K4: h1[dst] += alpha * h[src]   (one wave per edge, 2 elems/lane)
__global__ void k_gat_scatter(const int* __restrict__ src, const int* __restrict__ dst,
                              const float* __restrict__ h, const float* __restrict__ exbuf,
                              const float* __restrict__ denom, float* __restrict__ h1, int nE) {
    long gid = (long)blockIdx.x * blockDim.x + threadIdx.x;
    int e = (int)(gid >> 6);
    int lane = (int)(gid & 63);
    if (e >= nE) return;
    int s, d;
    if (e < NE) { s = src[e]; d = dst[e]; } else { s = d = e - NE; }
    float alpha = exbuf[e] / denom[d];
    const float* hr = h + (size_t)s * HID;
    float* o = h1 + (size_t)d * HID;
    atomicAdd(&o[lane], alpha * hr[lane]);
    atomicAdd(&o[lane + 64], alpha * hr[lane + 64]);
}

// K5: h1 = relu(h1 + b_gat)
__global__ void k_gat_post(float* __restrict__ h1, const float* __restrict__ b) {
    int i = blockIdx.x * blockDim.x + threadIdx.x;
    float v = h1[i] + b[i & (HID - 1)];
    h1[i] = v > 0.f ? v : 0.f;
}

// K6: msum[dst] += h1[src]; cnt[dst] += 1   (one wave per edge)
__global__ void k_sage_scatter(const int* __restrict__ src, const int* __restrict__ dst,
                               const float* __restrict__ h1, float* __restrict__ msum,
                               float* __restrict__ cnt) {
    long gid = (long)blockIdx.x * blockDim.x + threadIdx.x;
    int e = (int)(gid >> 6);
    int lane = (int)(gid & 63);
    if (e >= NE) return;
    int s = src[e], d = dst[e];
    const float* hr = h1 + (size_t)s * HID;
    float* o = msum + (size_t)d * HID;
    atomicAdd(&o[lane], hr[lane]);
    atomicAdd(&o[lane + 64], hr[lane + 64]);
    if (lane == 0) atomicAdd(&cnt[d], 1.f);
}

// K7: out = sigmoid( relu(mean @ W_l + b_l + h1 @ W_r) @ W_out + b_out )
__global__ void k_sage_out(const float* __restrict__ msum, const float* __restrict__ cnt,
                           const float* __restrict__ h1, const float* __restrict__ Wl,
                           const float* __restrict__ bl, const float* __restrict__ Wr,
                           const float* __restrict__ Wout, const float* __restrict__ bout,
                           float* __restrict__ out) {
    int row = blockIdx.x;
    int t = threadIdx.x;
    __shared__ float mrow[HID];
    __shared__ float srow[HID];
    float inv = 1.f / fmaxf(cnt[row], 1.f);
    mrow[t] = msum[(size_t)row * HID + t] * inv;
    srow[t] = h1[(size_t)row * HID + t];
    __syncthreads();
    float acc = 0.f;
#pragma unroll 8
    for (int k = 0; k < HID; ++k)
        acc = fmaf(mrow[k], Wl[k * HID + t], fmaf(srow[k], Wr[k * HID + t], acc));
    acc += bl[t];
    acc = fmaxf(acc, 0.f);
    float p = acc * Wout[t];
    for (int o = 32; o > 0; o >>= 1) p += __shfl_down(p, o);
    __shared__ float r[2];
    if ((t & 63) == 0) r[t >> 6] = p;
    __syncthreads();
    if (t == 0) {
        float z = r[0] + r[1] + bout[0];
        out[row] = 1.f / (1.f + __expf(-z));
    }
}

extern "C" void kernel_launch(void* const* d_in, const int* in_sizes, int n_in,
                              void* d_out, int out_size, void* d_ws, size_t ws_size,
                              hipStream_t stream) {
    const float* x    = (const float*)d_in[0];
    const int*   ei   = (const int*)d_in[1];
    const float* Wg   = (const float*)d_in[2];
    const float* a_s  = (const float*)d_in[3];
    const float* a_d  = (const float*)d_in[4];
    const float* bg   = (const float*)d_in[5];
    const float* Wl   = (const float*)d_in[6];
    const float* bl   = (const float*)d_in[7];
    const float* Wr   = (const float*)d_in[8];
    const float* Wout = (const float*)d_in[9];
    const float* bout = (const float*)d_in[10];
    float* out = (float*)d_out;

    const int* src = ei;
    const int* dst = ei + NE;
    int nE = NE + NN;

    // workspace layout
    float* ws    = (float*)d_ws;
    float* h     = ws;                    // NN*HID
    float* hs    = h + (size_t)NN * HID;  // NN
    float* hd    = hs + NN;               // NN
    float* exbuf = hd + NN;               // NE+NN
    // ---- zeroed region start ----
    unsigned* lmaxk = (unsigned*)(exbuf + nE); // NN
    float* denom = (float*)(lmaxk + NN);  // NN
    float* cnt   = denom + NN;            // NN
    float* h1    = cnt + NN;              // NN*HID
    float* msum  = h1 + (size_t)NN * HID; // NN*HID
    size_t zero_bytes = ((size_t)3 * NN + (size_t)2 * NN * HID) * sizeof(float);
    hipMemsetAsync(lmaxk, 0, zero_bytes, stream);

    k_gat_in<<<NN, 128, 0, stream>>>(x, Wg, a_s, a_d, h, hs, hd);
    k_logit_max<<<(nE + 255) / 256, 256, 0, stream>>>(src, dst, hs, hd, exbuf, lmaxk, nE);
    k_exp_sum<<<(nE + 255) / 256, 256, 0, stream>>>(dst, lmaxk, exbuf, denom, nE);

    long tot = (long)nE * 64;
    k_gat_scatter<<<(int)((tot + 255) / 256), 256, 0, stream>>>(src, dst, h, exbuf, denom, h1, nE);
    k_gat_post<<<(NN * HID) / 256, 256, 0, stream>>>(h1, bg);

    long tot2 = (long)NE * 64;
    k_sage_scatter<<<(int)((tot2 + 255) / 256), 256, 0, stream>>>(src, dst, h1, msum, cnt);
    k_sage_out<<<NN, 128, 0, stream>>>(msum, cnt, h1, Wl, bl, Wr, Wout, bout, out);
}

// Round 2
// 447.525 us; speedup vs baseline: 1.9418x; 1.9418x over previous
//
#include <hip/hip_runtime.h>

#define NN 50000
#define NE 600000
#define F_IN 57
#define HID 128
#define NEG 0.2f
#define NB_SCAN ((NN + 255) / 256)   // 196 blocks of 256 for the degree scan

// ---------------- K1: h = x @ W_gat ; hs = h.a_src ; hd = h.a_dst ----------------
__global__ void k_gat_in(const float* __restrict__ x, const float* __restrict__ Wg,
                         const float* __restrict__ a_s, const float* __restrict__ a_d,
                         float* __restrict__ h, float* __restrict__ hs, float* __restrict__ hd) {
    int row = blockIdx.x;
    int t = threadIdx.x;
    __shared__ float xs[F_IN];
    if (t < F_IN) xs[t] = x[row * F_IN + t];
    __syncthreads();
    float acc = 0.f;
#pragma unroll
    for (int k = 0; k < F_IN; ++k) acc = fmaf(xs[k], Wg[k * HID + t], acc);
    h[(size_t)row * HID + t] = acc;
    float ps = acc * a_s[t];
    float pd = acc * a_d[t];
    for (int o = 32; o > 0; o >>= 1) { ps += __shfl_down(ps, o); pd += __shfl_down(pd, o); }
    __shared__ float r[4];
    int w = t >> 6;
    if ((t & 63) == 0) { r[w] = ps; r[2 + w] = pd; }
    __syncthreads();
    if (t == 0) { hs[row] = r[0] + r[1]; hd[row] = r[2] + r[3]; }
}

// ---------------- CSR build ----------------
__global__ void k_hist(const int* __restrict__ dst, int* __restrict__ deg) {
    int e = blockIdx.x * blockDim.x + threadIdx.x;
    if (e < NE) atomicAdd(&deg[dst[e]], 1);
}

// per-256-block inclusive scan of deg -> exclusive written to rptr (pre block-offset), block totals to bsum
__global__ void k_scan1(const int* __restrict__ deg, int* __restrict__ rptr, int* __restrict__ bsum) {
    int t = threadIdx.x;
    int i = blockIdx.x * 256 + t;
    int v = (i < NN) ? deg[i] : 0;
    __shared__ int s[256];
    s[t] = v;
    __syncthreads();
    for (int off = 1; off < 256; off <<= 1) {
        int x = (t >= off) ? s[t - off] : 0;
        __syncthreads();
        s[t] += x;
        __syncthreads();
    }
    if (i < NN) rptr[i] = s[t] - v;          // exclusive within block
    if (t == 255) bsum[blockIdx.x] = s[255]; // block total
}

__global__ void k_scan2(int* __restrict__ bsum, int* __restrict__ bpre) {
    int t = threadIdx.x;
    int v = (t < NB_SCAN) ? bsum[t] : 0;
    __shared__ int s[256];
    s[t] = v;
    __syncthreads();
    for (int off = 1; off < 256; off <<= 1) {
        int x = (t >= off) ? s[t - off] : 0;
        __syncthreads();
        s[t] += x;
        __syncthreads();
    }
    if (t < NB_SCAN) bpre[t] = s[t] - v;     // exclusive block prefix
}

__global__ void k_scan3(int* __restrict__ rptr, const int* __restrict__ bpre) {
    int i = blockIdx.x * 256 + threadIdx.x;
    if (i < NN) rptr[i] += bpre[blockIdx.x];
}

__global__ void k_fill(const int* __restrict__ src, const int* __restrict__ dst,
                       const int* __restrict__ rptr, int* __restrict__ fill,
                       int* __restrict__ esrc) {
    int e = blockIdx.x * blockDim.x + threadIdx.x;
    if (e >= NE) return;
    int d = dst[e];
    int pos = rptr[d] + atomicAdd(&fill[d], 1);
    esrc[pos] = src[e];
}

// ---------------- GAT aggregation: block per node, online softmax over CSR edges ----------------
__global__ void k_gat_agg(const int* __restrict__ rptr, const int* __restrict__ deg,
                          const int* __restrict__ esrc, const float* __restrict__ hs,
                          const float* __restrict__ hd, const float* __restrict__ h,
                          const float* __restrict__ bg, float* __restrict__ h1) {
    int row = blockIdx.x;
    int t = threadIdx.x;
    float hdr = hd[row];
    // self-loop first: logit_self = leaky(hs[row]+hd[row]), weight 1 at running max
    float l = hs[row] + hdr;
    float m = (l >= 0.f) ? l : NEG * l;
    float den = 1.f;
    float acc = h[(size_t)row * HID + t];
    int start = rptr[row];
    int end = start + deg[row];
    for (int e = start; e < end; ++e) {
        int s = esrc[e];
        float lv = hs[s] + hdr;
        lv = (lv >= 0.f) ? lv : NEG * lv;
        float w;
        if (lv > m) {
            float scale = __expf(m - lv);
            den *= scale;
            acc *= scale;
            m = lv;
            w = 1.f;
        } else {
            w = __expf(lv - m);
        }
        den += w;
        acc = fmaf(w, h[(size_t)s * HID + t], acc);
    }
    float v = acc / den + bg[t];
    h1[(size_t)row * HID + t] = v > 0.f ? v : 0.f;
}

// ---------------- SAGE fused: mean-agg + dual matvec + ReLU + output head ----------------
__global__ void k_sage_fused(const int* __restrict__ rptr, const int* __restrict__ deg,
                             const int* __restrict__ esrc, const float* __restrict__ h1,
                             const float* __restrict__ Wl, const float* __restrict__ bl,
                             const float* __restrict__ Wr, const float* __restrict__ Wout,
                             const float* __restrict__ bout, float* __restrict__ out) {
    int row = blockIdx.x;
    int t = threadIdx.x;
    int start = rptr[row];
    int dn = deg[row];
    float acc = 0.f;
    for (int e = start; e < start + dn; ++e)
        acc += h1[(size_t)esrc[e] * HID + t];
    float mean = acc / (float)(dn > 0 ? dn : 1);
    __shared__ float mrow[HID];
    __shared__ float srow[HID];
    mrow[t] = mean;
    srow[t] = h1[(size_t)row * HID + t];
    __syncthreads();
    float o = 0.f;
#pragma unroll 8
    for (int k = 0; k < HID; ++k)
        o = fmaf(mrow[k], Wl[k * HID + t], fmaf(srow[k], Wr[k * HID + t], o));
    o += bl[t];
    o = fmaxf(o, 0.f);
    float p = o * Wout[t];
    for (int off = 32; off > 0; off >>= 1) p += __shfl_down(p, off);
    __shared__ float r[2];
    if ((t & 63) == 0) r[t >> 6] = p;
    __syncthreads();
    if (t == 0) {
        float z = r[0] + r[1] + bout[0];
        out[row] = 1.f / (1.f + __expf(-z));
    }
}

extern "C" void kernel_launch(void* const* d_in, const int* in_sizes, int n_in,
                              void* d_out, int out_size, void* d_ws, size_t ws_size,
                              hipStream_t stream) {
    const float* x    = (const float*)d_in[0];
    const int*   ei   = (const int*)d_in[1];
    const float* Wg   = (const float*)d_in[2];
    const float* a_s  = (const float*)d_in[3];
    const float* a_d  = (const float*)d_in[4];
    const float* bg   = (const float*)d_in[5];
    const float* Wl   = (const float*)d_in[6];
    const float* bl   = (const float*)d_in[7];
    const float* Wr   = (const float*)d_in[8];
    const float* Wout = (const float*)d_in[9];
    const float* bout = (const float*)d_in[10];
    float* out = (float*)d_out;

    const int* src = ei;
    const int* dst = ei + NE;

    // workspace layout
    float* h  = (float*)d_ws;                 // NN*HID
    float* h1 = h + (size_t)NN * HID;         // NN*HID
    float* hs = h1 + (size_t)NN * HID;        // NN
    float* hd = hs + NN;                      // NN
    int* deg  = (int*)(hd + NN);              // NN  (zeroed)
    int* fill = deg + NN;                     // NN  (zeroed)
    int* rptr = fill + NN;                    // NN
    int* bsum = rptr + NN;                    // NB_SCAN
    int* bpre = bsum + NB_SCAN;               // NB_SCAN
    int* esrc = bpre + NB_SCAN;               // NE

    hipMemsetAsync(deg, 0, (size_t)2 * NN * sizeof(int), stream);

    k_gat_in<<<NN, 128, 0, stream>>>(x, Wg, a_s, a_d, h, hs, hd);

    k_hist<<<(NE + 255) / 256, 256, 0, stream>>>(dst, deg);
    k_scan1<<<NB_SCAN, 256, 0, stream>>>(deg, rptr, bsum);
    k_scan2<<<1, 256, 0, stream>>>(bsum, bpre);
    k_scan3<<<NB_SCAN, 256, 0, stream>>>(rptr, bpre);
    k_fill<<<(NE + 255) / 256, 256, 0, stream>>>(src, dst, rptr, fill, esrc);

    k_gat_agg<<<NN, 128, 0, stream>>>(rptr, deg, esrc, hs, hd, h, bg, h1);
    k_sage_fused<<<NN, 128, 0, stream>>>(rptr, deg, esrc, h1, Wl, bl, Wr, Wout, bout, out);
}

// Round 3
// 307.547 us; speedup vs baseline: 2.8256x; 1.4551x over previous
//
#include <hip/hip_runtime.h>

#define NN 50000
#define NE 600000
#define F_IN 57
#define HID 128
#define NEG 0.2f
#define NB_SCAN ((NN + 255) / 256)
#define TN 32                      // nodes per dense-kernel block
#define NB_DENSE ((NN + TN - 1) / TN)

__device__ __forceinline__ float leaky(float v) { return v >= 0.f ? v : NEG * v; }

// ---------------- K1: h = x @ W_gat ; hs = h.a_src ; hd = h.a_dst ----------------
__global__ void k_gat_in(const float* __restrict__ x, const float* __restrict__ Wg,
                         const float* __restrict__ a_s, const float* __restrict__ a_d,
                         float* __restrict__ h, float* __restrict__ hs, float* __restrict__ hd) {
    int row = blockIdx.x;
    int t = threadIdx.x;
    __shared__ float xs[F_IN];
    if (t < F_IN) xs[t] = x[row * F_IN + t];
    __syncthreads();
    float acc = 0.f;
#pragma unroll
    for (int k = 0; k < F_IN; ++k) acc = fmaf(xs[k], Wg[k * HID + t], acc);
    h[(size_t)row * HID + t] = acc;
    float ps = acc * a_s[t];
    float pd = acc * a_d[t];
    for (int o = 32; o > 0; o >>= 1) { ps += __shfl_down(ps, o); pd += __shfl_down(pd, o); }
    __shared__ float r[4];
    int w = t >> 6;
    if ((t & 63) == 0) { r[w] = ps; r[2 + w] = pd; }
    __syncthreads();
    if (t == 0) { hs[row] = r[0] + r[1]; hd[row] = r[2] + r[3]; }
}

// ---------------- CSR build ----------------
__global__ void k_hist(const int* __restrict__ dst, int* __restrict__ deg) {
    int e = blockIdx.x * blockDim.x + threadIdx.x;
    if (e < NE) atomicAdd(&deg[dst[e]], 1);
}

__global__ void k_scan1(const int* __restrict__ deg, int* __restrict__ rptr, int* __restrict__ bsum) {
    int t = threadIdx.x;
    int i = blockIdx.x * 256 + t;
    int v = (i < NN) ? deg[i] : 0;
    __shared__ int s[256];
    s[t] = v;
    __syncthreads();
    for (int off = 1; off < 256; off <<= 1) {
        int x = (t >= off) ? s[t - off] : 0;
        __syncthreads();
        s[t] += x;
        __syncthreads();
    }
    if (i < NN) rptr[i] = s[t] - v;
    if (t == 255) bsum[blockIdx.x] = s[255];
}

__global__ void k_scan2(int* __restrict__ bsum, int* __restrict__ bpre) {
    int t = threadIdx.x;
    int v = (t < NB_SCAN) ? bsum[t] : 0;
    __shared__ int s[256];
    s[t] = v;
    __syncthreads();
    for (int off = 1; off < 256; off <<= 1) {
        int x = (t >= off) ? s[t - off] : 0;
        __syncthreads();
        s[t] += x;
        __syncthreads();
    }
    if (t < NB_SCAN) bpre[t] = s[t] - v;
}

__global__ void k_scan3(int* __restrict__ rptr, const int* __restrict__ bpre) {
    int i = blockIdx.x * 256 + threadIdx.x;
    if (i < NN) rptr[i] += bpre[blockIdx.x];
}

__global__ void k_fill(const int* __restrict__ src, const int* __restrict__ dst,
                       const int* __restrict__ rptr, int* __restrict__ fill,
                       int* __restrict__ esrc) {
    int e = blockIdx.x * blockDim.x + threadIdx.x;
    if (e >= NE) return;
    int d = dst[e];
    int pos = rptr[d] + atomicAdd(&fill[d], 1);
    esrc[pos] = src[e];
}

// ---------------- GAT aggregation: two-pass softmax, 4-way unrolled gather ----------------
__global__ void k_gat_agg(const int* __restrict__ rptr, const int* __restrict__ deg,
                          const int* __restrict__ esrc, const float* __restrict__ hs,
                          const float* __restrict__ hd, const float* __restrict__ h,
                          const float* __restrict__ bg, float* __restrict__ h1) {
    int row = blockIdx.x;
    int t = threadIdx.x;
    int start = rptr[row];
    int dn = deg[row];
    int end = start + dn;
    float hdr = hd[row];
    float lself = leaky(hs[row] + hdr);
    float m = lself;
    // pass 1: exact max over incoming logits (redundant across threads; loads are broadcast)
    int e = start;
    for (; e + 4 <= end; e += 4) {
        int s0 = esrc[e], s1 = esrc[e + 1], s2 = esrc[e + 2], s3 = esrc[e + 3];
        float l0 = leaky(hs[s0] + hdr), l1 = leaky(hs[s1] + hdr);
        float l2 = leaky(hs[s2] + hdr), l3 = leaky(hs[s3] + hdr);
        m = fmaxf(m, fmaxf(fmaxf(l0, l1), fmaxf(l2, l3)));
    }
    for (; e < end; ++e) m = fmaxf(m, leaky(hs[esrc[e]] + hdr));
    // pass 2: accumulate
    float wself = __expf(lself - m);
    float den = wself;
    float acc = wself * h[(size_t)row * HID + t];
    e = start;
    for (; e + 4 <= end; e += 4) {
        int s0 = esrc[e], s1 = esrc[e + 1], s2 = esrc[e + 2], s3 = esrc[e + 3];
        float w0 = __expf(leaky(hs[s0] + hdr) - m);
        float w1 = __expf(leaky(hs[s1] + hdr) - m);
        float w2 = __expf(leaky(hs[s2] + hdr) - m);
        float w3 = __expf(leaky(hs[s3] + hdr) - m);
        acc = fmaf(w0, h[(size_t)s0 * HID + t], acc);
        acc = fmaf(w1, h[(size_t)s1 * HID + t], acc);
        acc = fmaf(w2, h[(size_t)s2 * HID + t], acc);
        acc = fmaf(w3, h[(size_t)s3 * HID + t], acc);
        den += w0 + w1 + w2 + w3;
    }
    for (; e < end; ++e) {
        int s = esrc[e];
        float w = __expf(leaky(hs[s] + hdr) - m);
        acc = fmaf(w, h[(size_t)s * HID + t], acc);
        den += w;
    }
    float v = acc / den + bg[t];
    h1[(size_t)row * HID + t] = v > 0.f ? v : 0.f;
}

// ---------------- SAGE mean gather (4-way unrolled) ----------------
__global__ void k_sage_gather(const int* __restrict__ rptr, const int* __restrict__ deg,
                              const int* __restrict__ esrc, const float* __restrict__ h1,
                              float* __restrict__ mean) {
    int row = blockIdx.x;
    int t = threadIdx.x;
    int start = rptr[row];
    int dn = deg[row];
    int end = start + dn;
    float acc = 0.f;
    int e = start;
    for (; e + 4 <= end; e += 4) {
        int s0 = esrc[e], s1 = esrc[e + 1], s2 = esrc[e + 2], s3 = esrc[e + 3];
        float v0 = h1[(size_t)s0 * HID + t];
        float v1 = h1[(size_t)s1 * HID + t];
        float v2 = h1[(size_t)s2 * HID + t];
        float v3 = h1[(size_t)s3 * HID + t];
        acc += v0 + v1 + v2 + v3;
    }
    for (; e < end; ++e) acc += h1[(size_t)esrc[e] * HID + t];
    mean[(size_t)row * HID + t] = acc / (float)(dn > 0 ? dn : 1);
}

// ---------------- Dense: out = sigmoid(relu(mean@Wl + bl + h1@Wr) @ Wout + bout) ----------------
// 256 threads, TN=32 nodes/block, 4 nodes x 4 feats per thread.
__global__ void k_dense(const float* __restrict__ mean, const float* __restrict__ h1,
                        const float* __restrict__ Wl, const float* __restrict__ bl,
                        const float* __restrict__ Wr, const float* __restrict__ Wout,
                        const float* __restrict__ bout, float* __restrict__ out) {
    int tid = threadIdx.x;
    int node0 = blockIdx.x * TN;
    __shared__ __align__(16) float aM[HID][36];
    __shared__ __align__(16) float aS[HID][36];
    // stage transposed activations: thread handles node n = tid>>3, float4-chunk kq = tid&7
    {
        int n = tid >> 3;
        int gn = node0 + n;
        if (gn >= NN) gn = NN - 1;
        const float4* mrow = (const float4*)(mean + (size_t)gn * HID);
        const float4* srow = (const float4*)(h1 + (size_t)gn * HID);
        int kq = tid & 7;
#pragma unroll
        for (int iter = 0; iter < 4; ++iter) {
            int k4 = kq + iter * 8;
            float4 v = mrow[k4];
            float4 w = srow[k4];
            int k = k4 * 4;
            aM[k][n] = v.x; aM[k + 1][n] = v.y; aM[k + 2][n] = v.z; aM[k + 3][n] = v.w;
            aS[k][n] = w.x; aS[k + 1][n] = w.y; aS[k + 2][n] = w.z; aS[k + 3][n] = w.w;
        }
    }
    __syncthreads();
    int nq = tid >> 5;        // 0..7 -> nodes nq*4..+3
    int fq = tid & 31;        // 0..31 -> feats fq*4..+3
    int f0 = fq * 4;
    int nb = nq * 4;
    float acc[4][4];
#pragma unroll
    for (int i = 0; i < 4; ++i)
#pragma unroll
        for (int j = 0; j < 4; ++j) acc[i][j] = 0.f;

#pragma unroll 2
    for (int k = 0; k < HID; ++k) {
        float4 wl = *(const float4*)(Wl + k * HID + f0);
        float4 wr = *(const float4*)(Wr + k * HID + f0);
        float4 am = *(const float4*)&aM[k][nb];
        float4 as = *(const float4*)&aS[k][nb];
        float mv[4] = {am.x, am.y, am.z, am.w};
        float sv[4] = {as.x, as.y, as.z, as.w};
        float wlv[4] = {wl.x, wl.y, wl.z, wl.w};
        float wrv[4] = {wr.x, wr.y, wr.z, wr.w};
#pragma unroll
        for (int i = 0; i < 4; ++i)
#pragma unroll
            for (int j = 0; j < 4; ++j)
                acc[i][j] = fmaf(mv[i], wlv[j], fmaf(sv[i], wrv[j], acc[i][j]));
    }

    float4 bias = *(const float4*)(bl + f0);
    float4 wo = *(const float4*)(Wout + f0);
    float bo = bout[0];
#pragma unroll
    for (int i = 0; i < 4; ++i) {
        float h0 = fmaxf(acc[i][0] + bias.x, 0.f);
        float h1v = fmaxf(acc[i][1] + bias.y, 0.f);
        float h2v = fmaxf(acc[i][2] + bias.z, 0.f);
        float h3v = fmaxf(acc[i][3] + bias.w, 0.f);
        float p = h0 * wo.x + h1v * wo.y + h2v * wo.z + h3v * wo.w;
#pragma unroll
        for (int off = 1; off < 32; off <<= 1) p += __shfl_xor(p, off);
        if (fq == 0) {
            int gn = node0 + nb + i;
            if (gn < NN) {
                float z = p + bo;
                out[gn] = 1.f / (1.f + __expf(-z));
            }
        }
    }
}

extern "C" void kernel_launch(void* const* d_in, const int* in_sizes, int n_in,
                              void* d_out, int out_size, void* d_ws, size_t ws_size,
                              hipStream_t stream) {
    const float* x    = (const float*)d_in[0];
    const int*   ei   = (const int*)d_in[1];
    const float* Wg   = (const float*)d_in[2];
    const float* a_s  = (const float*)d_in[3];
    const float* a_d  = (const float*)d_in[4];
    const float* bg   = (const float*)d_in[5];
    const float* Wl   = (const float*)d_in[6];
    const float* bl   = (const float*)d_in[7];
    const float* Wr   = (const float*)d_in[8];
    const float* Wout = (const float*)d_in[9];
    const float* bout = (const float*)d_in[10];
    float* out = (float*)d_out;

    const int* src = ei;
    const int* dst = ei + NE;

    // workspace layout
    float* h  = (float*)d_ws;                 // NN*HID  (reused as `mean` after GAT)
    float* h1 = h + (size_t)NN * HID;         // NN*HID
    float* hs = h1 + (size_t)NN * HID;        // NN
    float* hd = hs + NN;                      // NN
    int* deg  = (int*)(hd + NN);              // NN  (zeroed)
    int* fill = deg + NN;                     // NN  (zeroed)
    int* rptr = fill + NN;                    // NN
    int* bsum = rptr + NN;                    // NB_SCAN
    int* bpre = bsum + NB_SCAN;               // NB_SCAN
    int* esrc = bpre + NB_SCAN;               // NE

    hipMemsetAsync(deg, 0, (size_t)2 * NN * sizeof(int), stream);

    k_gat_in<<<NN, 128, 0, stream>>>(x, Wg, a_s, a_d, h, hs, hd);

    k_hist<<<(NE + 255) / 256, 256, 0, stream>>>(dst, deg);
    k_scan1<<<NB_SCAN, 256, 0, stream>>>(deg, rptr, bsum);
    k_scan2<<<1, 256, 0, stream>>>(bsum, bpre);
    k_scan3<<<NB_SCAN, 256, 0, stream>>>(rptr, bpre);
    k_fill<<<(NE + 255) / 256, 256, 0, stream>>>(src, dst, rptr, fill, esrc);

    k_gat_agg<<<NN, 128, 0, stream>>>(rptr, deg, esrc, hs, hd, h, bg, h1);
    float* mean = h;  // h is dead after k_gat_agg
    k_sage_gather<<<NN, 128, 0, stream>>>(rptr, deg, esrc, h1, mean);
    k_dense<<<NB_DENSE, 256, 0, stream>>>(mean, h1, Wl, bl, Wr, Wout, bout, out);
}

// Round 4
// 278.364 us; speedup vs baseline: 3.1219x; 1.1048x over previous
//
#include <hip/hip_runtime.h>

#define NN 50000
#define NE 600000
#define F_IN 57
#define HID 128
#define NEG 0.2f
#define NB_SCAN ((NN + 255) / 256)

#define GIN_NODES 64
#define NB_GIN ((NN + GIN_NODES - 1) / GIN_NODES)
#define XST 68                 // xsT row stride (floats), even+16B-align friendly

#define TN 32                  // nodes per dense block
#define NB_DENSE ((NN + TN - 1) / TN)
#define AST 132                // activation row stride (floats): 128+4, 16B aligned

__device__ __forceinline__ float leaky(float v) { return v >= 0.f ? v : NEG * v; }

// ---------------- K1: tiled  h = x @ W_gat ; hs = h.a_src ; hd = h.a_dst ----------------
// 64 nodes/block, 256 threads. Wg staged once per block (kills 1.46 GB L2 weight re-stream).
__global__ __launch_bounds__(256) void k_gat_in(
    const float* __restrict__ x, const float* __restrict__ Wg,
    const float* __restrict__ a_s, const float* __restrict__ a_d,
    float* __restrict__ h, float* __restrict__ hs, float* __restrict__ hd) {
    __shared__ float WgS[F_IN * HID];      // 29184 B
    __shared__ float xsT[F_IN][XST];       // 15504 B  (transposed x tile)
    int tid = threadIdx.x;
    int node0 = blockIdx.x * GIN_NODES;

    // stage Wg (coalesced float4)
    {
        const float4* g = (const float4*)Wg;
        float4* s = (float4*)WgS;
        for (int i = tid; i < F_IN * HID / 4; i += 256) s[i] = g[i];
    }
    // stage x transposed: xsT[k][n]
    for (int i = tid; i < GIN_NODES * F_IN; i += 256) {
        int n = i / F_IN;
        int k = i - n * F_IN;
        int gn = node0 + n;
        if (gn >= NN) gn = NN - 1;
        xsT[k][n] = x[gn * F_IN + k];
    }
    __syncthreads();

    int fq = tid & 31, nq = tid >> 5;
    int f0 = fq * 4, nb = nq * 8;
    float acc[8][4];
#pragma unroll
    for (int i = 0; i < 8; ++i)
#pragma unroll
        for (int j = 0; j < 4; ++j) acc[i][j] = 0.f;

    for (int k = 0; k < F_IN; ++k) {
        float4 w = *(const float4*)&WgS[k * HID + f0];
        float4 xa = *(const float4*)&xsT[k][nb];
        float4 xb = *(const float4*)&xsT[k][nb + 4];
        float xv[8] = {xa.x, xa.y, xa.z, xa.w, xb.x, xb.y, xb.z, xb.w};
        float wv[4] = {w.x, w.y, w.z, w.w};
#pragma unroll
        for (int i = 0; i < 8; ++i)
#pragma unroll
            for (int j = 0; j < 4; ++j)
                acc[i][j] = fmaf(xv[i], wv[j], acc[i][j]);
    }

    // write h + fused attention dots
    float4 as4 = *(const float4*)(a_s + f0);
    float4 ad4 = *(const float4*)(a_d + f0);
    float ps[8], pd[8];
#pragma unroll
    for (int i = 0; i < 8; ++i) {
        int gn = node0 + nb + i;
        if (gn < NN) {
            float4 v = {acc[i][0], acc[i][1], acc[i][2], acc[i][3]};
            *(float4*)(h + (size_t)gn * HID + f0) = v;
        }
        ps[i] = acc[i][0] * as4.x + acc[i][1] * as4.y + acc[i][2] * as4.z + acc[i][3] * as4.w;
        pd[i] = acc[i][0] * ad4.x + acc[i][1] * ad4.y + acc[i][2] * ad4.z + acc[i][3] * ad4.w;
    }
#pragma unroll
    for (int off = 16; off > 0; off >>= 1) {
#pragma unroll
        for (int i = 0; i < 8; ++i) {
            ps[i] += __shfl_xor(ps[i], off);
            pd[i] += __shfl_xor(pd[i], off);
        }
    }
    if (fq == 0) {
#pragma unroll
        for (int i = 0; i < 8; ++i) {
            int gn = node0 + nb + i;
            if (gn < NN) { hs[gn] = ps[i]; hd[gn] = pd[i]; }
        }
    }
}

// ---------------- CSR build ----------------
__global__ void k_hist(const int* __restrict__ dst, int* __restrict__ deg) {
    int e = blockIdx.x * blockDim.x + threadIdx.x;
    if (e < NE) atomicAdd(&deg[dst[e]], 1);
}

__global__ void k_scan1(const int* __restrict__ deg, int* __restrict__ rptr, int* __restrict__ bsum) {
    int t = threadIdx.x;
    int i = blockIdx.x * 256 + t;
    int v = (i < NN) ? deg[i] : 0;
    __shared__ int s[256];
    s[t] = v;
    __syncthreads();
    for (int off = 1; off < 256; off <<= 1) {
        int x = (t >= off) ? s[t - off] : 0;
        __syncthreads();
        s[t] += x;
        __syncthreads();
    }
    if (i < NN) rptr[i] = s[t] - v;
    if (t == 255) bsum[blockIdx.x] = s[255];
}

__global__ void k_scan2(int* __restrict__ bsum, int* __restrict__ bpre) {
    int t = threadIdx.x;
    int v = (t < NB_SCAN) ? bsum[t] : 0;
    __shared__ int s[256];
    s[t] = v;
    __syncthreads();
    for (int off = 1; off < 256; off <<= 1) {
        int x = (t >= off) ? s[t - off] : 0;
        __syncthreads();
        s[t] += x;
        __syncthreads();
    }
    if (t < NB_SCAN) bpre[t] = s[t] - v;
}

__global__ void k_scan3(int* __restrict__ rptr, const int* __restrict__ bpre) {
    int i = blockIdx.x * 256 + threadIdx.x;
    if (i < NN) rptr[i] += bpre[blockIdx.x];
}

__global__ void k_fill(const int* __restrict__ src, const int* __restrict__ dst,
                       const int* __restrict__ rptr, int* __restrict__ fill,
                       int* __restrict__ esrc) {
    int e = blockIdx.x * blockDim.x + threadIdx.x;
    if (e >= NE) return;
    int d = dst[e];
    int pos = rptr[d] + atomicAdd(&fill[d], 1);
    esrc[pos] = src[e];
}

// ---------------- GAT aggregation: two-pass softmax, 4-way unrolled gather ----------------
__global__ void k_gat_agg(const int* __restrict__ rptr, const int* __restrict__ deg,
                          const int* __restrict__ esrc, const float* __restrict__ hs,
                          const float* __restrict__ hd, const float* __restrict__ h,
                          const float* __restrict__ bg, float* __restrict__ h1) {
    int row = blockIdx.x;
    int t = threadIdx.x;
    int start = rptr[row];
    int dn = deg[row];
    int end = start + dn;
    float hdr = hd[row];
    float lself = leaky(hs[row] + hdr);
    float m = lself;
    int e = start;
    for (; e + 4 <= end; e += 4) {
        int s0 = esrc[e], s1 = esrc[e + 1], s2 = esrc[e + 2], s3 = esrc[e + 3];
        float l0 = leaky(hs[s0] + hdr), l1 = leaky(hs[s1] + hdr);
        float l2 = leaky(hs[s2] + hdr), l3 = leaky(hs[s3] + hdr);
        m = fmaxf(m, fmaxf(fmaxf(l0, l1), fmaxf(l2, l3)));
    }
    for (; e < end; ++e) m = fmaxf(m, leaky(hs[esrc[e]] + hdr));
    float wself = __expf(lself - m);
    float den = wself;
    float acc = wself * h[(size_t)row * HID + t];
    e = start;
    for (; e + 4 <= end; e += 4) {
        int s0 = esrc[e], s1 = esrc[e + 1], s2 = esrc[e + 2], s3 = esrc[e + 3];
        float w0 = __expf(leaky(hs[s0] + hdr) - m);
        float w1 = __expf(leaky(hs[s1] + hdr) - m);
        float w2 = __expf(leaky(hs[s2] + hdr) - m);
        float w3 = __expf(leaky(hs[s3] + hdr) - m);
        acc = fmaf(w0, h[(size_t)s0 * HID + t], acc);
        acc = fmaf(w1, h[(size_t)s1 * HID + t], acc);
        acc = fmaf(w2, h[(size_t)s2 * HID + t], acc);
        acc = fmaf(w3, h[(size_t)s3 * HID + t], acc);
        den += w0 + w1 + w2 + w3;
    }
    for (; e < end; ++e) {
        int s = esrc[e];
        float w = __expf(leaky(hs[s] + hdr) - m);
        acc = fmaf(w, h[(size_t)s * HID + t], acc);
        den += w;
    }
    float v = acc / den + bg[t];
    h1[(size_t)row * HID + t] = v > 0.f ? v : 0.f;
}

// ---------------- SAGE mean gather (4-way unrolled) ----------------
__global__ void k_sage_gather(const int* __restrict__ rptr, const int* __restrict__ deg,
                              const int* __restrict__ esrc, const float* __restrict__ h1,
                              float* __restrict__ mean) {
    int row = blockIdx.x;
    int t = threadIdx.x;
    int start = rptr[row];
    int dn = deg[row];
    int end = start + dn;
    float acc = 0.f;
    int e = start;
    for (; e + 4 <= end; e += 4) {
        int s0 = esrc[e], s1 = esrc[e + 1], s2 = esrc[e + 2], s3 = esrc[e + 3];
        float v0 = h1[(size_t)s0 * HID + t];
        float v1 = h1[(size_t)s1 * HID + t];
        float v2 = h1[(size_t)s2 * HID + t];
        float v3 = h1[(size_t)s3 * HID + t];
        acc += v0 + v1 + v2 + v3;
    }
    for (; e < end; ++e) acc += h1[(size_t)esrc[e] * HID + t];
    mean[(size_t)row * HID + t] = acc / (float)(dn > 0 ? dn : 1);
}

// ---------------- Dense: out = sigmoid(relu(mean@Wl + bl + h1@Wr) @ Wout + bout) ----------------
// 256 threads, TN=32 nodes/block. Direct LDS layout [node][k] (broadcast float4 reads),
// 33.8 KB LDS -> 4 blocks/CU.
__global__ __launch_bounds__(256, 4) void k_dense(
    const float* __restrict__ mean, const float* __restrict__ h1,
    const float* __restrict__ Wl, const float* __restrict__ bl,
    const float* __restrict__ Wr, const float* __restrict__ Wout,
    const float* __restrict__ bout, float* __restrict__ out) {
    __shared__ __align__(16) float aM[TN][AST];
    __shared__ __align__(16) float aS[TN][AST];
    int tid = threadIdx.x;
    int node0 = blockIdx.x * TN;
    {
        int n = tid >> 3;
        int kq = tid & 7;
        int gn = node0 + n;
        if (gn >= NN) gn = NN - 1;
        const float4* mrow = (const float4*)(mean + (size_t)gn * HID);
        const float4* srow = (const float4*)(h1 + (size_t)gn * HID);
#pragma unroll
        for (int iter = 0; iter < 4; ++iter) {
            int k4 = kq + iter * 8;
            *(float4*)&aM[n][k4 * 4] = mrow[k4];
            *(float4*)&aS[n][k4 * 4] = srow[k4];
        }
    }
    __syncthreads();

    int nq = tid >> 5;        // 0..7 -> 4 nodes each
    int fq = tid & 31;        // 0..31 -> 4 feats each
    int f0 = fq * 4;
    int nb = nq * 4;
    float acc[4][4];
#pragma unroll
    for (int i = 0; i < 4; ++i)
#pragma unroll
        for (int j = 0; j < 4; ++j) acc[i][j] = 0.f;

#pragma unroll 2
    for (int kq = 0; kq < HID / 4; ++kq) {
        int k0 = kq * 4;
        float am[4][4], as_[4][4];
#pragma unroll
        for (int i = 0; i < 4; ++i) {
            float4 tm = *(const float4*)&aM[nb + i][k0];
            float4 ts = *(const float4*)&aS[nb + i][k0];
            am[i][0] = tm.x; am[i][1] = tm.y; am[i][2] = tm.z; am[i][3] = tm.w;
            as_[i][0] = ts.x; as_[i][1] = ts.y; as_[i][2] = ts.z; as_[i][3] = ts.w;
        }
#pragma unroll
        for (int j = 0; j < 4; ++j) {
            int k = k0 + j;
            float4 wl = *(const float4*)(Wl + k * HID + f0);
            float4 wr = *(const float4*)(Wr + k * HID + f0);
            float wlv[4] = {wl.x, wl.y, wl.z, wl.w};
            float wrv[4] = {wr.x, wr.y, wr.z, wr.w};
#pragma unroll
            for (int i = 0; i < 4; ++i)
#pragma unroll
                for (int jf = 0; jf < 4; ++jf)
                    acc[i][jf] = fmaf(am[i][j], wlv[jf], fmaf(as_[i][j], wrv[jf], acc[i][jf]));
        }
    }

    float4 bias = *(const float4*)(bl + f0);
    float4 wo = *(const float4*)(Wout + f0);
    float bo = bout[0];
#pragma unroll
    for (int i = 0; i < 4; ++i) {
        float h0 = fmaxf(acc[i][0] + bias.x, 0.f);
        float h1v = fmaxf(acc[i][1] + bias.y, 0.f);
        float h2v = fmaxf(acc[i][2] + bias.z, 0.f);
        float h3v = fmaxf(acc[i][3] + bias.w, 0.f);
        float p = h0 * wo.x + h1v * wo.y + h2v * wo.z + h3v * wo.w;
#pragma unroll
        for (int off = 16; off > 0; off >>= 1) p += __shfl_xor(p, off);
        if (fq == 0) {
            int gn = node0 + nb + i;
            if (gn < NN) {
                float z = p + bo;
                out[gn] = 1.f / (1.f + __expf(-z));
            }
        }
    }
}

extern "C" void kernel_launch(void* const* d_in, const int* in_sizes, int n_in,
                              void* d_out, int out_size, void* d_ws, size_t ws_size,
                              hipStream_t stream) {
    const float* x    = (const float*)d_in[0];
    const int*   ei   = (const int*)d_in[1];
    const float* Wg   = (const float*)d_in[2];
    const float* a_s  = (const float*)d_in[3];
    const float* a_d  = (const float*)d_in[4];
    const float* bg   = (const float*)d_in[5];
    const float* Wl   = (const float*)d_in[6];
    const float* bl   = (const float*)d_in[7];
    const float* Wr   = (const float*)d_in[8];
    const float* Wout = (const float*)d_in[9];
    const float* bout = (const float*)d_in[10];
    float* out = (float*)d_out;

    const int* src = ei;
    const int* dst = ei + NE;

    float* h  = (float*)d_ws;                 // NN*HID  (reused as `mean` after GAT)
    float* h1 = h + (size_t)NN * HID;         // NN*HID
    float* hs = h1 + (size_t)NN * HID;        // NN
    float* hd = hs + NN;                      // NN
    int* deg  = (int*)(hd + NN);              // NN  (zeroed)
    int* fill = deg + NN;                     // NN  (zeroed)
    int* rptr = fill + NN;                    // NN
    int* bsum = rptr + NN;                    // NB_SCAN
    int* bpre = bsum + NB_SCAN;               // NB_SCAN
    int* esrc = bpre + NB_SCAN;               // NE

    hipMemsetAsync(deg, 0, (size_t)2 * NN * sizeof(int), stream);

    k_gat_in<<<NB_GIN, 256, 0, stream>>>(x, Wg, a_s, a_d, h, hs, hd);

    k_hist<<<(NE + 255) / 256, 256, 0, stream>>>(dst, deg);
    k_scan1<<<NB_SCAN, 256, 0, stream>>>(deg, rptr, bsum);
    k_scan2<<<1, 256, 0, stream>>>(bsum, bpre);
    k_scan3<<<NB_SCAN, 256, 0, stream>>>(rptr, bpre);
    k_fill<<<(NE + 255) / 256, 256, 0, stream>>>(src, dst, rptr, fill, esrc);

    k_gat_agg<<<NN, 128, 0, stream>>>(rptr, deg, esrc, hs, hd, h, bg, h1);
    float* mean = h;  // h is dead after k_gat_agg
    k_sage_gather<<<NN, 128, 0, stream>>>(rptr, deg, esrc, h1, mean);
    k_dense<<<NB_DENSE, 256, 0, stream>>>(mean, h1, Wl, bl, Wr, Wout, bout, out);
}